// Round 3
// baseline (286.198 us; speedup 1.0000x reference)
//
#include <hip/hip_runtime.h>
#include <hip/hip_cooperative_groups.h>
#include <math.h>

namespace cg = cooperative_groups;

#define N_NODES 1024
#define N_EDGES 32768
#define FEAT    384

// One cooperative kernel, 256 blocks x 512 threads (1 block/CU, co-resident).
// Phases separated by grid.sync(); LDS region reused across phases.
__global__ __launch_bounds__(512, 1) void k_mega(
        const float* __restrict__ feat, const int* __restrict__ ei,
        const float* __restrict__ eattr,
        const float* __restrict__ Wk, const float* __restrict__ Wq,
        const float* __restrict__ Wv,
        const float* __restrict__ Ek, const float* __restrict__ Eq,
        const float* __restrict__ Ev,
        const float* __restrict__ bias, const float* __restrict__ mult,
        float* __restrict__ q, float* __restrict__ k, float* __restrict__ v,
        float* __restrict__ A, float* __restrict__ S, float* __restrict__ wbuf,
        float* __restrict__ M) {
    cg::grid_group grid = cg::this_grid();
    __shared__ __align__(16) float sm[8704];    // 34816 B (P1 is the max user)
    const int tid  = threadIdx.x;
    const int bid  = blockIdx.x;
    const int lane = tid & 63;
    const int wave = tid >> 6;

    // ---- P0: q,k,v = feat @ {Wq,Wk,Wv}  (4 rows/block); block 0 zeroes S ----
    {
        float* fs = sm;                          // [4][FEAT]
        const int row0 = bid * 4;
        if (tid < 384)
            ((float4*)fs)[tid] = ((const float4*)(feat + (size_t)row0 * FEAT))[tid];
        if (bid == 0 && tid >= 384)
            for (int i = tid - 384; i < 2 * N_NODES; i += 128) S[i] = 0.f;
        __syncthreads();
        if (tid < 384) {
            const int mat = tid >> 7;            // wave-uniform: 0=q,1=k,2=v
            const int sub = tid & 127;
            const int col = sub & 63;
            const int rh  = sub >> 6;            // rows rh*2, rh*2+1
            const float* W  = (mat == 0) ? Wq : (mat == 1 ? Wk : Wv);
            const float* f0 = fs + (rh * 2) * FEAT;
            const float* f1 = fs + (rh * 2 + 1) * FEAT;
            float a0 = 0.f, a1 = 0.f;
            #pragma unroll 8
            for (int f = 0; f < FEAT; ++f) {
                float wv = W[f * 64 + col];
                a0 = fmaf(f0[f], wv, a0);
                a1 = fmaf(f1[f], wv, a1);
            }
            float* out = (mat == 0) ? q : (mat == 1 ? k : v);
            out[(row0 + rh * 2 + 0) * 64 + col] = a0;
            out[(row0 + rh * 2 + 1) * 64 + col] = a1;
        }
    }
    grid.sync();

    // ---- P1: A = 2 * q @ k^T.  One 64x64 tile per block (16x16 grid). ----
    {
        float* qs = sm;                          // [64][68]
        float* ks = sm + 4352;                   // [64][68], ks[kk][col]
        const int rowbase = (bid >> 4) * 64;
        const int colbase = (bid & 15) * 64;
        for (int idx = tid; idx < 4096; idx += 512) {
            int r = idx >> 6, c = idx & 63;
            qs[r * 68 + c] = q[(rowbase + r) * 64 + c];
            ks[c * 68 + r] = k[(colbase + r) * 64 + c];
        }
        __syncthreads();
        const int tx = tid & 15, ty = tid >> 4;  // ty 0..31
        float acc[2][4] = {};
        for (int kk = 0; kk < 64; ++kk) {
            float a0 = qs[(ty * 2 + 0) * 68 + kk];
            float a1 = qs[(ty * 2 + 1) * 68 + kk];
            float4 b = *(const float4*)&ks[kk * 68 + tx * 4];
            acc[0][0] = fmaf(a0, b.x, acc[0][0]); acc[0][1] = fmaf(a0, b.y, acc[0][1]);
            acc[0][2] = fmaf(a0, b.z, acc[0][2]); acc[0][3] = fmaf(a0, b.w, acc[0][3]);
            acc[1][0] = fmaf(a1, b.x, acc[1][0]); acc[1][1] = fmaf(a1, b.y, acc[1][1]);
            acc[1][2] = fmaf(a1, b.z, acc[1][2]); acc[1][3] = fmaf(a1, b.w, acc[1][3]);
        }
        #pragma unroll
        for (int i = 0; i < 2; ++i) {
            float4 o = make_float4(2.f * acc[i][0], 2.f * acc[i][1],
                                   2.f * acc[i][2], 2.f * acc[i][3]);
            *(float4*)&A[(size_t)(rowbase + ty * 2 + i) * N_NODES + colbase + tx * 4] = o;
        }
    }
    grid.sync();

    // ---- P2: per-edge scatter into A (+ save sigmoid w).  16 edges/wave. ----
    {
        const int gw = (bid << 3) | wave;        // global wave id, 0..2047
        const float b0 = bias[0], mu = mult[0];
        const float ek0 = Ek[lane], ek1 = Ek[64 + lane];
        const float eq0 = Eq[lane], eq1 = Eq[64 + lane];
        #pragma unroll 2
        for (int i = 0; i < 16; ++i) {
            const int e = gw + i * 2048;
            const int src = ei[e], dst = ei[N_EDGES + e];
            const float w  = 1.0f / (1.0f + expf(-(eattr[e] - b0) * mu));
            const float rk = truncf(w * ek0 + (1.0f - w) * ek1);
            const float rq = truncf(w * eq0 + (1.0f - w) * eq1);
            float c = q[src * 64 + lane] * rk + k[dst * 64 + lane] * rq;
            #pragma unroll
            for (int off = 32; off >= 1; off >>= 1) c += __shfl_xor(c, off, 64);
            if (lane == 0) {
                atomicAdd(&A[(size_t)src * N_NODES + dst], c);
                wbuf[e] = w;
            }
        }
    }
    grid.sync();

    // ---- P3: row softmax of A/sqrt(384), in place.  128 threads per row. ----
    {
        const int g   = tid >> 7;                // row group 0..3 (2 waves)
        const int lt  = tid & 127;
        const int row = bid * 4 + g;
        float4* Ar = (float4*)(A + (size_t)row * N_NODES);
        float4 x0 = Ar[lt * 2], x1 = Ar[lt * 2 + 1];
        const float inv_s = 0.05103103630798287f;   // 1/sqrt(384)
        float m = fmaxf(fmaxf(fmaxf(x0.x, x0.y), fmaxf(x0.z, x0.w)),
                        fmaxf(fmaxf(x1.x, x1.y), fmaxf(x1.z, x1.w)));
        #pragma unroll
        for (int off = 32; off >= 1; off >>= 1) m = fmaxf(m, __shfl_xor(m, off, 64));
        if (lane == 0) sm[wave] = m;
        __syncthreads();
        m = fmaxf(sm[g * 2], sm[g * 2 + 1]);
        float e0 = expf((x0.x - m) * inv_s), e1 = expf((x0.y - m) * inv_s);
        float e2 = expf((x0.z - m) * inv_s), e3 = expf((x0.w - m) * inv_s);
        float e4 = expf((x1.x - m) * inv_s), e5 = expf((x1.y - m) * inv_s);
        float e6 = expf((x1.z - m) * inv_s), e7 = expf((x1.w - m) * inv_s);
        float s = ((e0 + e1) + (e2 + e3)) + ((e4 + e5) + (e6 + e7));
        #pragma unroll
        for (int off = 32; off >= 1; off >>= 1) s += __shfl_xor(s, off, 64);
        if (lane == 0) sm[8 + wave] = s;
        __syncthreads();
        s = sm[8 + g * 2] + sm[8 + g * 2 + 1];
        const float rs = 1.0f / s;
        Ar[lt * 2 + 0] = make_float4(e0 * rs, e1 * rs, e2 * rs, e3 * rs);
        Ar[lt * 2 + 1] = make_float4(e4 * rs, e5 * rs, e6 * rs, e7 * rs);
    }
    grid.sync();

    // ---- P4: S0[r] = sum A[r,dst]*w, S1[r] = sum A[r,dst]*(1-w). ----
    {
        const int e = bid * 512 + tid;
        if (e < N_EDGES) {
            const int src = ei[e], dst = ei[N_EDGES + e];
            const float w = wbuf[e];
            const float a = A[(size_t)src * N_NODES + dst];
            atomicAdd(&S[src * 2 + 0], a * w);
            atomicAdd(&S[src * 2 + 1], a * (1.0f - w));
        }
    }
    grid.sync();

    // ---- P5: M = A @ v + S0*Ev0 + S1*Ev1.  4 rows/block, 8-way j-split. ----
    {
        float* As  = sm;                         // [4][1024]
        float* red = sm + 4096;                  // [4][8][64]
        const int row0 = bid * 4;
        for (int idx = tid; idx < 1024; idx += 512)
            ((float4*)As)[idx] = ((const float4*)(A + (size_t)row0 * N_NODES))[idx];
        __syncthreads();
        const int jbase = wave * 128;
        const int d = lane;
        float a0 = 0.f, a1 = 0.f, a2 = 0.f, a3 = 0.f;
        #pragma unroll 2
        for (int j0 = 0; j0 < 128; j0 += 4) {
            const int j = jbase + j0;
            float4 c0 = *(const float4*)&As[0 * 1024 + j];
            float4 c1 = *(const float4*)&As[1 * 1024 + j];
            float4 c2 = *(const float4*)&As[2 * 1024 + j];
            float4 c3 = *(const float4*)&As[3 * 1024 + j];
            float v0 = v[(j + 0) * 64 + d];
            float v1 = v[(j + 1) * 64 + d];
            float v2 = v[(j + 2) * 64 + d];
            float v3 = v[(j + 3) * 64 + d];
            a0 = fmaf(c0.x, v0, a0); a0 = fmaf(c0.y, v1, a0);
            a0 = fmaf(c0.z, v2, a0); a0 = fmaf(c0.w, v3, a0);
            a1 = fmaf(c1.x, v0, a1); a1 = fmaf(c1.y, v1, a1);
            a1 = fmaf(c1.z, v2, a1); a1 = fmaf(c1.w, v3, a1);
            a2 = fmaf(c2.x, v0, a2); a2 = fmaf(c2.y, v1, a2);
            a2 = fmaf(c2.z, v2, a2); a2 = fmaf(c2.w, v3, a2);
            a3 = fmaf(c3.x, v0, a3); a3 = fmaf(c3.y, v1, a3);
            a3 = fmaf(c3.z, v2, a3); a3 = fmaf(c3.w, v3, a3);
        }
        red[(0 * 8 + wave) * 64 + d] = a0;
        red[(1 * 8 + wave) * 64 + d] = a1;
        red[(2 * 8 + wave) * 64 + d] = a2;
        red[(3 * 8 + wave) * 64 + d] = a3;
        __syncthreads();
        if (tid < 256) {
            const int r = tid >> 6, dd = tid & 63;
            float acc = 0.f;
            #pragma unroll
            for (int wv = 0; wv < 8; ++wv) acc += red[(r * 8 + wv) * 64 + dd];
            const int row = row0 + r;
            acc += S[row * 2 + 0] * Ev[dd] + S[row * 2 + 1] * Ev[64 + dd];
            M[row * 64 + dd] = acc;
        }
    }
}

// ---------------------------------------------------------------------------
extern "C" void kernel_launch(void* const* d_in, const int* in_sizes, int n_in,
                              void* d_out, int out_size, void* d_ws, size_t ws_size,
                              hipStream_t stream) {
    (void)in_sizes; (void)n_in; (void)out_size; (void)ws_size;
    const float* feat  = (const float*)d_in[0];
    const int*   ei    = (const int*)d_in[1];
    const float* eattr = (const float*)d_in[2];
    const float* Wk    = (const float*)d_in[3];
    const float* Wq    = (const float*)d_in[4];
    const float* Wv    = (const float*)d_in[5];
    const float* Ek    = (const float*)d_in[6];
    const float* Eq    = (const float*)d_in[7];
    const float* Ev    = (const float*)d_in[8];
    const float* bias  = (const float*)d_in[9];
    const float* mult  = (const float*)d_in[10];
    float* M = (float*)d_out;

    float* wsf = (float*)d_ws;
    float* q    = wsf;                      // 1024*64
    float* k    = wsf + 65536;              // 1024*64
    float* v    = wsf + 131072;             // 1024*64
    float* A    = wsf + 196608;             // 1024*1024
    float* S    = wsf + 196608 + 1048576;   // 2048
    float* wbuf = S + 2048;                 // 32768

    void* args[] = {(void*)&feat, (void*)&ei, (void*)&eattr,
                    (void*)&Wk, (void*)&Wq, (void*)&Wv,
                    (void*)&Ek, (void*)&Eq, (void*)&Ev,
                    (void*)&bias, (void*)&mult,
                    (void*)&q, (void*)&k, (void*)&v,
                    (void*)&A, (void*)&S, (void*)&wbuf, (void*)&M};
    hipLaunchCooperativeKernel((const void*)k_mega, dim3(256), dim3(512),
                               args, 0, stream);
}

// Round 4
// 168.453 us; speedup vs baseline: 1.6990x; 1.6990x over previous
//
#include <hip/hip_runtime.h>
#include <math.h>

#define N_NODES 1024
#define N_EDGES 32768
#define FEAT    384

// ---------------------------------------------------------------------------
// K1: q,k,v = feat @ {Wq,Wk,Wv}.  256 blocks x 384 thr, 4 rows/block.
// ---------------------------------------------------------------------------
__global__ __launch_bounds__(384) void k_kqv(
        const float* __restrict__ feat,
        const float* __restrict__ Wk, const float* __restrict__ Wq,
        const float* __restrict__ Wv,
        float* __restrict__ q, float* __restrict__ k, float* __restrict__ v) {
    __shared__ float fs[4 * FEAT];
    const int tid = threadIdx.x;
    const int row0 = blockIdx.x * 4;
    ((float4*)fs)[tid] = ((const float4*)(feat + (size_t)row0 * FEAT))[tid];
    __syncthreads();
    const int mat = tid >> 7;           // 0=q, 1=k, 2=v (128 threads each)
    const int sub = tid & 127;
    const int col = sub & 63;
    const int rh  = sub >> 6;           // rows rh*2, rh*2+1
    const float* W  = (mat == 0) ? Wq : (mat == 1 ? Wk : Wv);
    const float* f0 = fs + (rh * 2) * FEAT;
    const float* f1 = fs + (rh * 2 + 1) * FEAT;
    float a0 = 0.f, a1 = 0.f;
    #pragma unroll 8
    for (int f = 0; f < FEAT; ++f) {
        float wv = W[f * 64 + col];
        a0 = fmaf(f0[f], wv, a0);
        a1 = fmaf(f1[f], wv, a1);
    }
    float* out = (mat == 0) ? q : (mat == 1 ? k : v);
    out[(row0 + rh * 2 + 0) * 64 + col] = a0;
    out[(row0 + rh * 2 + 1) * 64 + col] = a1;
}

// ---------------------------------------------------------------------------
// K2: CSR build (by src) in ONE block: LDS histogram -> scan -> fill.
// Independent of k_kqv (only reads ei).
// ---------------------------------------------------------------------------
__global__ __launch_bounds__(1024) void k_csr(
        const int* __restrict__ ei, int* __restrict__ offs,
        int* __restrict__ eids) {
    __shared__ int hist[1024];
    __shared__ int scan[1024];
    const int t = threadIdx.x;
    hist[t] = 0;
    __syncthreads();
    #pragma unroll 4
    for (int i = 0; i < 32; ++i)
        atomicAdd(&hist[ei[t + i * 1024]], 1);
    __syncthreads();
    scan[t] = hist[t];
    __syncthreads();
    for (int off = 1; off < 1024; off <<= 1) {
        int val = (t >= off) ? scan[t - off] : 0;
        __syncthreads();
        scan[t] += val;
        __syncthreads();
    }
    offs[t + 1] = scan[t];
    if (t == 0) offs[0] = 0;
    hist[t] = scan[t] - hist[t];        // exclusive prefix = fill cursor
    __syncthreads();
    #pragma unroll 4
    for (int i = 0; i < 32; ++i) {
        const int e = t + i * 1024;
        const int pos = atomicAdd(&hist[ei[e]], 1);
        eids[pos] = e;
    }
}

// ---------------------------------------------------------------------------
// K3: the row kernel.  Each block owns 4 rows of A end-to-end:
//   A-rows = 2*q@k^T (k streamed through swizzled LDS chunk)
//   + edge deltas (CSR, LDS atomics)  -> softmax in LDS
//   -> S0/S1 locally -> M = A@v (v streamed) + S*Ev.   A never hits global.
// ---------------------------------------------------------------------------
__global__ __launch_bounds__(512) void k_row(
        const float* __restrict__ q, const float* __restrict__ k,
        const float* __restrict__ v,
        const int* __restrict__ ei, const float* __restrict__ eattr,
        const float* __restrict__ Ek, const float* __restrict__ Eq,
        const float* __restrict__ Ev,
        const float* __restrict__ bias, const float* __restrict__ mult,
        const int* __restrict__ offs, const int* __restrict__ eids,
        float* __restrict__ M) {
    __shared__ float As[4][1024];               // 16 KB (logits -> probs)
    __shared__ float qr[4][64];                 // 1 KB
    __shared__ __align__(16) float chunk[128 * 68];   // 34.8 KB: ks[64][128] / vs[128][68]
    __shared__ float redm[8], reds[8];
    __shared__ float sred[8][2];
    __shared__ float sS[4][2];

    const int tid  = threadIdx.x;
    const int lane = tid & 63;
    const int wave = tid >> 6;
    const int row0 = blockIdx.x * 4;

    if (tid < 256) qr[tid >> 6][tid & 63] = q[(row0 + (tid >> 6)) * 64 + (tid & 63)];
    __syncthreads();

    // ---- QKT: As[g][j] = 2 * q[row0+g] . k[j], 8 chunks of 128 k-rows ----
    const int g  = tid >> 7;                    // row 0..3
    const int c0 = tid & 127;                   // col-in-chunk
    const int lc  = tid >> 4;                   // loader: 0..31
    const int lk4 = (tid & 15) * 4;             // loader: kk base
    const int lsw = ((lk4 >> 2) & 7) << 2;      // XOR swizzle (store side)
    for (int ch = 0; ch < 8; ++ch) {
        const int jb = ch * 128;
        #pragma unroll
        for (int it = 0; it < 4; ++it) {
            const int cc = lc + it * 32;
            float4 kv = *(const float4*)&k[(size_t)(jb + cc) * 64 + lk4];
            const int csw = cc ^ lsw;
            chunk[(lk4 + 0) * 128 + csw] = kv.x;
            chunk[(lk4 + 1) * 128 + csw] = kv.y;
            chunk[(lk4 + 2) * 128 + csw] = kv.z;
            chunk[(lk4 + 3) * 128 + csw] = kv.w;
        }
        __syncthreads();
        float acc = 0.f;
        #pragma unroll
        for (int kk = 0; kk < 64; kk += 4) {
            const int cs = c0 ^ (((kk >> 2) & 7) << 2);
            float4 qv = *(const float4*)&qr[g][kk];
            acc = fmaf(qv.x, chunk[(kk + 0) * 128 + cs], acc);
            acc = fmaf(qv.y, chunk[(kk + 1) * 128 + cs], acc);
            acc = fmaf(qv.z, chunk[(kk + 2) * 128 + cs], acc);
            acc = fmaf(qv.w, chunk[(kk + 3) * 128 + cs], acc);
        }
        As[g][jb + c0] = 2.f * acc;
        __syncthreads();                        // before chunk overwrite
    }

    // ---- edge deltas: As[rl][dst] += q[row].trunc(rk) + k[dst].trunc(rq) ----
    {
        const int rl  = wave >> 1;              // local row 0..3
        const int sub = wave & 1;
        const int row = row0 + rl;
        const float b0 = bias[0], mu = mult[0];
        const float ek0 = Ek[lane], ek1 = Ek[64 + lane];
        const float eq0 = Eq[lane], eq1 = Eq[64 + lane];
        const int beg = offs[row], end = offs[row + 1];
        for (int p = beg + sub; p < end; p += 2) {
            const int e = eids[p];
            const int dst = ei[N_EDGES + e];
            const float w  = 1.0f / (1.0f + expf(-(eattr[e] - b0) * mu));
            const float rk = truncf(w * ek0 + (1.0f - w) * ek1);
            const float rq = truncf(w * eq0 + (1.0f - w) * eq1);
            float c = qr[rl][lane] * rk + k[(size_t)dst * 64 + lane] * rq;
            #pragma unroll
            for (int off = 32; off >= 1; off >>= 1) c += __shfl_xor(c, off, 64);
            if (lane == 0) atomicAdd(&As[rl][dst], c);
        }
    }
    __syncthreads();

    // ---- softmax (rows by 128-thread groups), probs stay in LDS ----
    {
        const int lt = tid & 127;
        float4 x0 = *(float4*)&As[g][lt * 8];
        float4 x1 = *(float4*)&As[g][lt * 8 + 4];
        const float inv_s = 0.05103103630798287f;   // 1/sqrt(384)
        float m = fmaxf(fmaxf(fmaxf(x0.x, x0.y), fmaxf(x0.z, x0.w)),
                        fmaxf(fmaxf(x1.x, x1.y), fmaxf(x1.z, x1.w)));
        #pragma unroll
        for (int off = 32; off >= 1; off >>= 1) m = fmaxf(m, __shfl_xor(m, off, 64));
        if (lane == 0) redm[wave] = m;
        __syncthreads();
        m = fmaxf(redm[g * 2], redm[g * 2 + 1]);
        float e0 = expf((x0.x - m) * inv_s), e1 = expf((x0.y - m) * inv_s);
        float e2 = expf((x0.z - m) * inv_s), e3 = expf((x0.w - m) * inv_s);
        float e4 = expf((x1.x - m) * inv_s), e5 = expf((x1.y - m) * inv_s);
        float e6 = expf((x1.z - m) * inv_s), e7 = expf((x1.w - m) * inv_s);
        float s = ((e0 + e1) + (e2 + e3)) + ((e4 + e5) + (e6 + e7));
        #pragma unroll
        for (int off = 32; off >= 1; off >>= 1) s += __shfl_xor(s, off, 64);
        if (lane == 0) reds[wave] = s;
        __syncthreads();
        s = reds[g * 2] + reds[g * 2 + 1];
        const float rs = 1.0f / s;
        *(float4*)&As[g][lt * 8]     = make_float4(e0 * rs, e1 * rs, e2 * rs, e3 * rs);
        *(float4*)&As[g][lt * 8 + 4] = make_float4(e4 * rs, e5 * rs, e6 * rs, e7 * rs);
    }
    __syncthreads();

    // ---- S0/S1 per row (edges strided across the row's 128 threads) ----
    {
        const int lt  = tid & 127;
        const int row = row0 + g;
        const float b0 = bias[0], mu = mult[0];
        const int beg = offs[row], end = offs[row + 1];
        float s0 = 0.f, s1 = 0.f;
        for (int p = beg + lt; p < end; p += 128) {
            const int e = eids[p];
            const int dst = ei[N_EDGES + e];
            const float w = 1.0f / (1.0f + expf(-(eattr[e] - b0) * mu));
            const float a = As[g][dst];
            s0 = fmaf(a, w, s0);
            s1 = fmaf(a, 1.0f - w, s1);
        }
        #pragma unroll
        for (int off = 32; off >= 1; off >>= 1) {
            s0 += __shfl_xor(s0, off, 64);
            s1 += __shfl_xor(s1, off, 64);
        }
        if (lane == 0) { sred[wave][0] = s0; sred[wave][1] = s1; }
        __syncthreads();
        if (tid < 4) {
            sS[tid][0] = sred[tid * 2][0] + sred[tid * 2 + 1][0];
            sS[tid][1] = sred[tid * 2][1] + sred[tid * 2 + 1][1];
        }
    }
    __syncthreads();

    // ---- M = As @ v + S0*Ev0 + S1*Ev1 (v streamed through chunk) ----
    {
        const int r = tid >> 6;                 // active tid<256: row r, dim d
        const int d = tid & 63;
        const int lj  = tid >> 4;               // loader: 0..31
        const int ld4 = (tid & 15) * 4;
        float acc = 0.f;
        for (int ch = 0; ch < 8; ++ch) {
            const int jb = ch * 128;
            #pragma unroll
            for (int it = 0; it < 4; ++it) {
                const int j = lj + it * 32;
                float4 vv = *(const float4*)&v[(size_t)(jb + j) * 64 + ld4];
                *(float4*)&chunk[j * 68 + ld4] = vv;
            }
            __syncthreads();
            if (tid < 256) {
                #pragma unroll 4
                for (int j = 0; j < 128; ++j)
                    acc = fmaf(As[r][jb + j], chunk[j * 68 + d], acc);
            }
            __syncthreads();
        }
        if (tid < 256) {
            acc += sS[r][0] * Ev[d] + sS[r][1] * Ev[64 + d];
            M[(row0 + r) * 64 + d] = acc;
        }
    }
}

// ---------------------------------------------------------------------------
extern "C" void kernel_launch(void* const* d_in, const int* in_sizes, int n_in,
                              void* d_out, int out_size, void* d_ws, size_t ws_size,
                              hipStream_t stream) {
    (void)in_sizes; (void)n_in; (void)out_size; (void)ws_size;
    const float* feat  = (const float*)d_in[0];
    const int*   ei    = (const int*)d_in[1];
    const float* eattr = (const float*)d_in[2];
    const float* Wk    = (const float*)d_in[3];
    const float* Wq    = (const float*)d_in[4];
    const float* Wv    = (const float*)d_in[5];
    const float* Ek    = (const float*)d_in[6];
    const float* Eq    = (const float*)d_in[7];
    const float* Ev    = (const float*)d_in[8];
    const float* bias  = (const float*)d_in[9];
    const float* mult  = (const float*)d_in[10];
    float* M = (float*)d_out;

    float* wsf = (float*)d_ws;
    float* q = wsf;                     // 1024*64
    float* k = wsf + 65536;             // 1024*64
    float* v = wsf + 131072;            // 1024*64
    int* offs = (int*)(wsf + 196608);   // 1025
    int* eids = offs + 1028;            // 32768

    k_kqv<<<256, 384, 0, stream>>>(feat, Wk, Wq, Wv, q, k, v);
    k_csr<<<1, 1024, 0, stream>>>(ei, offs, eids);
    k_row<<<256, 512, 0, stream>>>(q, k, v, ei, eattr, Ek, Eq, Ev,
                                   bias, mult, offs, eids, M);
}

// Round 5
// 128.602 us; speedup vs baseline: 2.2255x; 1.3099x over previous
//
#include <hip/hip_runtime.h>
#include <math.h>

#define N_NODES 1024
#define N_EDGES 32768
#define FEAT    384
#define INV_S   0.05103103630798287f   // 1/sqrt(384)

// ---------------------------------------------------------------------------
// K1: q,k,v = feat @ {Wq,Wk,Wv}.  256 blocks x 384 thr, 4 rows/block.
// ---------------------------------------------------------------------------
__global__ __launch_bounds__(384) void k_kqv(
        const float* __restrict__ feat,
        const float* __restrict__ Wk, const float* __restrict__ Wq,
        const float* __restrict__ Wv,
        float* __restrict__ q, float* __restrict__ k, float* __restrict__ v) {
    __shared__ float fs[4 * FEAT];
    const int tid = threadIdx.x;
    const int row0 = blockIdx.x * 4;
    ((float4*)fs)[tid] = ((const float4*)(feat + (size_t)row0 * FEAT))[tid];
    __syncthreads();
    const int mat = tid >> 7;           // 0=q, 1=k, 2=v (128 threads each)
    const int sub = tid & 127;
    const int col = sub & 63;
    const int rh  = sub >> 6;           // rows rh*2, rh*2+1
    const float* W  = (mat == 0) ? Wq : (mat == 1 ? Wk : Wv);
    const float* f0 = fs + (rh * 2) * FEAT;
    const float* f1 = fs + (rh * 2 + 1) * FEAT;
    float a0 = 0.f, a1 = 0.f;
    #pragma unroll 8
    for (int f = 0; f < FEAT; ++f) {
        float wv = W[f * 64 + col];
        a0 = fmaf(f0[f], wv, a0);
        a1 = fmaf(f1[f], wv, a1);
    }
    float* out = (mat == 0) ? q : (mat == 1 ? k : v);
    out[(row0 + rh * 2 + 0) * 64 + col] = a0;
    out[(row0 + rh * 2 + 1) * 64 + col] = a1;
}

// ---------------------------------------------------------------------------
// K2: A = 2 * q @ k^T (logits).  64x64 tile/block, 4x4 microtile, padded LDS.
// ---------------------------------------------------------------------------
__global__ __launch_bounds__(256) void k_qkt(
        const float* __restrict__ q, const float* __restrict__ k,
        float* __restrict__ A) {
    __shared__ float qs[64][65];
    __shared__ float kst[64][65];   // kst[kk][col]
    const int tid = threadIdx.x;
    const int rowbase = blockIdx.y * 64, colbase = blockIdx.x * 64;
    for (int idx = tid; idx < 4096; idx += 256) {
        int r = idx >> 6, c = idx & 63;
        qs[r][c] = q[(rowbase + r) * 64 + c];
        kst[c][r] = k[(colbase + r) * 64 + c];
    }
    __syncthreads();
    const int tx = tid & 15, ty = tid >> 4;
    float acc[4][4] = {};
    for (int kk = 0; kk < 64; ++kk) {
        float a0 = qs[ty * 4 + 0][kk], a1 = qs[ty * 4 + 1][kk];
        float a2 = qs[ty * 4 + 2][kk], a3 = qs[ty * 4 + 3][kk];
        float b0 = kst[kk][tx * 4 + 0], b1 = kst[kk][tx * 4 + 1];
        float b2 = kst[kk][tx * 4 + 2], b3 = kst[kk][tx * 4 + 3];
        acc[0][0] = fmaf(a0, b0, acc[0][0]); acc[0][1] = fmaf(a0, b1, acc[0][1]);
        acc[0][2] = fmaf(a0, b2, acc[0][2]); acc[0][3] = fmaf(a0, b3, acc[0][3]);
        acc[1][0] = fmaf(a1, b0, acc[1][0]); acc[1][1] = fmaf(a1, b1, acc[1][1]);
        acc[1][2] = fmaf(a1, b2, acc[1][2]); acc[1][3] = fmaf(a1, b3, acc[1][3]);
        acc[2][0] = fmaf(a2, b0, acc[2][0]); acc[2][1] = fmaf(a2, b1, acc[2][1]);
        acc[2][2] = fmaf(a2, b2, acc[2][2]); acc[2][3] = fmaf(a2, b3, acc[2][3]);
        acc[3][0] = fmaf(a3, b0, acc[3][0]); acc[3][1] = fmaf(a3, b1, acc[3][1]);
        acc[3][2] = fmaf(a3, b2, acc[3][2]); acc[3][3] = fmaf(a3, b3, acc[3][3]);
    }
    for (int i = 0; i < 4; ++i) {
        float4 o = make_float4(2.f * acc[i][0], 2.f * acc[i][1],
                               2.f * acc[i][2], 2.f * acc[i][3]);
        *(float4*)&A[(size_t)(rowbase + ty * 4 + i) * N_NODES + colbase + tx * 4] = o;
    }
}

// ---------------------------------------------------------------------------
// K3: per-edge logit deltas: A[src,dst] += q[src].trunc(rk) + k[dst].trunc(rq)
// One 64-lane wave per edge, shuffle-reduce, one atomic.
// ---------------------------------------------------------------------------
__global__ __launch_bounds__(256) void k_edgeA(
        const int* __restrict__ ei, const float* __restrict__ eattr,
        const float* __restrict__ Ek, const float* __restrict__ Eq,
        const float* __restrict__ q, const float* __restrict__ k,
        const float* __restrict__ bias, const float* __restrict__ mult,
        float* __restrict__ A) {
    const int e = (blockIdx.x * 256 + threadIdx.x) >> 6;
    const int lane = threadIdx.x & 63;
    const int src = ei[e], dst = ei[N_EDGES + e];
    const float w  = 1.0f / (1.0f + expf(-(eattr[e] - bias[0]) * mult[0]));
    const float w1 = 1.0f - w;
    const float rk = truncf(w * Ek[lane] + w1 * Ek[64 + lane]);
    const float rq = truncf(w * Eq[lane] + w1 * Eq[64 + lane]);
    float c = q[src * 64 + lane] * rk + k[dst * 64 + lane] * rq;
    #pragma unroll
    for (int off = 32; off >= 1; off >>= 1) c += __shfl_xor(c, off, 64);
    if (lane == 0) atomicAdd(&A[(size_t)src * N_NODES + dst], c);
}

// ---------------------------------------------------------------------------
// K4: per 2 rows: softmax stats (m, 1/sum -> rowstats), probs in LDS,
//     M = probs @ v (v streamed through LDS in 128-row chunks).
// A stays as logits in global; 512 blocks x 256 threads.
// ---------------------------------------------------------------------------
__global__ __launch_bounds__(256) void k_avsm(
        const float* __restrict__ A, const float* __restrict__ v,
        float* __restrict__ rowstats, float* __restrict__ M) {
    __shared__ float As[2][1024];                     // 8 KB: logits -> probs
    __shared__ __align__(16) float chunk[128 * 68];   // 34.8 KB
    __shared__ float redm[4], reds[4];
    __shared__ float red[2][2][64];
    const int tid  = threadIdx.x;
    const int lane = tid & 63;
    const int wave = tid >> 6;
    const int row0 = blockIdx.x * 2;

    #pragma unroll
    for (int i = 0; i < 2; ++i) {
        const int idx = tid + i * 256;
        ((float4*)As)[idx] = ((const float4*)(A + (size_t)row0 * N_NODES))[idx];
    }
    __syncthreads();

    // softmax: row g handled by 128 threads (2 waves), 8 elems each
    const int g  = tid >> 7;
    const int lt = tid & 127;
    {
        float4 x0 = *(float4*)&As[g][lt * 8];
        float4 x1 = *(float4*)&As[g][lt * 8 + 4];
        float m = fmaxf(fmaxf(fmaxf(x0.x, x0.y), fmaxf(x0.z, x0.w)),
                        fmaxf(fmaxf(x1.x, x1.y), fmaxf(x1.z, x1.w)));
        #pragma unroll
        for (int off = 32; off >= 1; off >>= 1) m = fmaxf(m, __shfl_xor(m, off, 64));
        if (lane == 0) redm[wave] = m;
        __syncthreads();
        m = fmaxf(redm[g * 2], redm[g * 2 + 1]);
        float e0 = expf((x0.x - m) * INV_S), e1 = expf((x0.y - m) * INV_S);
        float e2 = expf((x0.z - m) * INV_S), e3 = expf((x0.w - m) * INV_S);
        float e4 = expf((x1.x - m) * INV_S), e5 = expf((x1.y - m) * INV_S);
        float e6 = expf((x1.z - m) * INV_S), e7 = expf((x1.w - m) * INV_S);
        float s = ((e0 + e1) + (e2 + e3)) + ((e4 + e5) + (e6 + e7));
        #pragma unroll
        for (int off = 32; off >= 1; off >>= 1) s += __shfl_xor(s, off, 64);
        if (lane == 0) reds[wave] = s;
        __syncthreads();
        s = reds[g * 2] + reds[g * 2 + 1];
        const float rs = 1.0f / s;
        if (lt == 0) {
            rowstats[(row0 + g) * 2 + 0] = m;
            rowstats[(row0 + g) * 2 + 1] = rs;
        }
        *(float4*)&As[g][lt * 8]     = make_float4(e0 * rs, e1 * rs, e2 * rs, e3 * rs);
        *(float4*)&As[g][lt * 8 + 4] = make_float4(e4 * rs, e5 * rs, e6 * rs, e7 * rs);
    }
    __syncthreads();

    // AV: wave w -> (row w>>1, j-half w&1); lane = output dim d
    const int r = wave >> 1, h = wave & 1, d = lane;
    float acc = 0.f;
    for (int ch = 0; ch < 8; ++ch) {
        const int jb = ch * 128;
        #pragma unroll
        for (int it = 0; it < 8; ++it) {
            const int idx = tid + it * 256;       // 0..2047
            const int j = idx >> 4, d4 = (idx & 15) * 4;
            *(float4*)&chunk[j * 68 + d4] =
                *(const float4*)&v[(size_t)(jb + j) * 64 + d4];
        }
        __syncthreads();
        const float* as = &As[r][jb + h * 64];
        const float* ck = &chunk[h * 64 * 68 + d];
        #pragma unroll 8
        for (int j = 0; j < 64; ++j)
            acc = fmaf(as[j], ck[j * 68], acc);
        __syncthreads();
    }
    red[r][h][d] = acc;
    __syncthreads();
    if (tid < 128) {
        const int rr = tid >> 6, dd = tid & 63;
        M[(row0 + rr) * 64 + dd] = red[rr][0][dd] + red[rr][1][dd];
    }
}

// ---------------------------------------------------------------------------
// K5: per-edge value term directly into M:
//   prob = exp((logit-m)*inv_s)*rs;  M[src,:] += prob*(w*Ev0 + (1-w)*Ev1)
// One wave per edge, one atomicAdd per lane.
// ---------------------------------------------------------------------------
__global__ __launch_bounds__(256) void k_edgeM(
        const int* __restrict__ ei, const float* __restrict__ eattr,
        const float* __restrict__ Ev, const float* __restrict__ bias,
        const float* __restrict__ mult,
        const float* __restrict__ A, const float* __restrict__ rowstats,
        float* __restrict__ M) {
    const int e = (blockIdx.x * 256 + threadIdx.x) >> 6;
    const int lane = threadIdx.x & 63;
    const int src = ei[e], dst = ei[N_EDGES + e];
    const float logit = A[(size_t)src * N_NODES + dst];
    const float m  = rowstats[src * 2 + 0];
    const float rs = rowstats[src * 2 + 1];
    const float prob = expf((logit - m) * INV_S) * rs;
    const float w = 1.0f / (1.0f + expf(-(eattr[e] - bias[0]) * mult[0]));
    const float rv = w * Ev[lane] + (1.0f - w) * Ev[64 + lane];
    atomicAdd(&M[src * 64 + lane], prob * rv);
}

// ---------------------------------------------------------------------------
extern "C" void kernel_launch(void* const* d_in, const int* in_sizes, int n_in,
                              void* d_out, int out_size, void* d_ws, size_t ws_size,
                              hipStream_t stream) {
    (void)in_sizes; (void)n_in; (void)out_size; (void)ws_size;
    const float* feat  = (const float*)d_in[0];
    const int*   ei    = (const int*)d_in[1];
    const float* eattr = (const float*)d_in[2];
    const float* Wk    = (const float*)d_in[3];
    const float* Wq    = (const float*)d_in[4];
    const float* Wv    = (const float*)d_in[5];
    const float* Ek    = (const float*)d_in[6];
    const float* Eq    = (const float*)d_in[7];
    const float* Ev    = (const float*)d_in[8];
    const float* bias  = (const float*)d_in[9];
    const float* mult  = (const float*)d_in[10];
    float* M = (float*)d_out;

    float* wsf = (float*)d_ws;
    float* q        = wsf;                      // 1024*64
    float* k        = wsf + 65536;              // 1024*64
    float* v        = wsf + 131072;             // 1024*64
    float* A        = wsf + 196608;             // 1024*1024
    float* rowstats = wsf + 196608 + 1048576;   // 2048

    k_kqv<<<256, 384, 0, stream>>>(feat, Wk, Wq, Wv, q, k, v);
    k_qkt<<<dim3(16, 16), 256, 0, stream>>>(q, k, A);
    k_edgeA<<<8192, 256, 0, stream>>>(ei, eattr, Ek, Eq, q, k, bias, mult, A);
    k_avsm<<<512, 256, 0, stream>>>(A, v, rowstats, M);
    k_edgeM<<<8192, 256, 0, stream>>>(ei, eattr, Ev, bias, mult, A, rowstats, M);
}